// Round 2
// baseline (978.284 us; speedup 1.0000x reference)
//
#include <hip/hip_runtime.h>
#include <math.h>

// ---- problem constants ----
#define TT 80
#define BS 8
#define NA 6
#define DMODEL 768
#define DH 192
#define FFD 1024
#define NROWS (TT*BS)   // 640
#define NQKV (3*DMODEL) // 2304
#define NTHREADS 320    // 5 waves
#define NBLOCKS 256     // 1 block/CU -> trivially co-resident

typedef __bf16 bf16;
typedef __bf16 bf16x8 __attribute__((ext_vector_type(8)));
typedef float  f32x4  __attribute__((ext_vector_type(4)));

struct MegaP {
    const float *x; const int *y; const int *ind_map; const int *act_ts;
    const float *skel_W, *skel_b, *muQ, *sigQ;
    const float *Wq, *bq, *Wk, *bk, *Wv, *bv, *Wo, *bo, *W1, *b1, *W2, *b2;
    const float *ln1_g, *ln1_b, *ln2_g, *ln2_b, *lnf_g, *lnf_b;
    float *out;
    float *h, *h1, *tmp;
    bf16 *qkvB, *hB, *h1B, *attB, *ffn1B, *qkvT, *woT, *w1T, *w2T;
    int *bar;
};

// ---------------- grid barrier (monotonic counter; agent scope) -------------
// Release on arrive flushes this XCD's L2 to the coherence point; acquire
// fence after the spin invalidates L1/L2 so post-barrier reads are fresh.
// Safe while #barriers < #blocks (29 << 256).
__device__ __forceinline__ void gbar(int* cnt, int target) {
    __syncthreads();
    if (threadIdx.x == 0) {
        __hip_atomic_fetch_add(cnt, 1, __ATOMIC_RELEASE, __HIP_MEMORY_SCOPE_AGENT);
        while (__hip_atomic_load(cnt, __ATOMIC_RELAXED, __HIP_MEMORY_SCOPE_AGENT) < target)
            __builtin_amdgcn_s_sleep(2);
        __threadfence();
    }
    __syncthreads();
}

// ---------------- stage 0: weight transpose->bf16 + embedding ---------------
// transpose jobs: per layer 3840 (QKV 1728, Wo 576, W1 768, W2 768); 4 layers
// = 15360.  embed jobs: 15360..15999 (one per (t,b) row).
__device__ void prep_stage(char* smem, const MegaP& P) {
    float (*tile)[33] = (float(*)[33])smem;          // 4224 B
    float* xrow = (float*)(smem + 8192);             // 600 B
    int tid = threadIdx.x;
#pragma unroll 1
    for (int job = blockIdx.x; job < 15360 + 640; job += gridDim.x) {
        if (job < 15360) {
            int l = job / 3840, r = job % 3840;
            const float* src; bf16* dst; int ldsrc, Kd, n0, ncol, k0;
            if (r < 1728) {                             // QKV: K=768, N=2304
                int kt = r % 24, nt = r / 24;
                k0 = kt * 32; n0 = nt * 32; Kd = 768; ldsrc = 768;
                dst = P.qkvT + (size_t)l * NQKV * DMODEL;
                if (n0 < 768)       { src = P.Wq + (size_t)l * 589824; ncol = n0; }
                else if (n0 < 1536) { src = P.Wk + (size_t)l * 589824; ncol = n0 - 768; }
                else                { src = P.Wv + (size_t)l * 589824; ncol = n0 - 1536; }
            } else if (r < 2304) {                      // Wo: 768x768
                int r2 = r - 1728; int kt = r2 % 24, nt = r2 / 24;
                k0 = kt * 32; n0 = nt * 32; ncol = n0; Kd = 768; ldsrc = 768;
                src = P.Wo + (size_t)l * 589824; dst = P.woT + (size_t)l * 589824;
            } else if (r < 3072) {                      // W1: K=768, N=1024
                int r2 = r - 2304; int kt = r2 % 24, nt = r2 / 24;
                k0 = kt * 32; n0 = nt * 32; ncol = n0; Kd = 768; ldsrc = 1024;
                src = P.W1 + (size_t)l * 786432; dst = P.w1T + (size_t)l * 786432;
            } else {                                    // W2: K=1024, N=768
                int r2 = r - 3072; int kt = r2 % 32, nt = r2 / 32;
                k0 = kt * 32; n0 = nt * 32; ncol = n0; Kd = 1024; ldsrc = 768;
                src = P.W2 + (size_t)l * 786432; dst = P.w2T + (size_t)l * 786432;
            }
            int tx = tid & 31, ty = tid >> 5;
            if (tid < 256) {
#pragma unroll
                for (int i = 0; i < 4; i++) {
                    int rr = ty + 8 * i;
                    tile[rr][tx] = src[(size_t)(k0 + rr) * ldsrc + ncol + tx];
                }
            }
            __syncthreads();
            if (tid < 256) {
#pragma unroll
                for (int i = 0; i < 4; i++) {
                    int rr = ty + 8 * i;
                    dst[(size_t)(n0 + rr) * Kd + k0 + tx] = (bf16)tile[tx][rr];
                }
            }
            __syncthreads();
        } else {
            int rr = job - 15360;
            int t = rr >> 3, b = rr & 7;
            int c = tid;
            if (c < 150) xrow[c] = P.x[(b * 150 + c) * TT + t];
            __syncthreads();
            if (c < 256) {
                float acc = P.skel_b[c];
                for (int jf = 0; jf < 150; jf++) acc += xrow[jf] * P.skel_W[jf * 256 + c];
                int ind_t = P.ind_map[t * 8 + b];
                int yb = P.y[b * NA + ind_t];
                float cm = P.muQ[yb * 256 + c];
                float cs = P.sigQ[yb * 256 + c];
                int start = (t == 0) ? 0 : (t + 2);
                float div = expf((float)(c & ~1) * (-9.210340371976184f / 256.0f));
                float p0, p1, p2;
                if (c & 1) {
                    p0 = cosf((float)start * div);
                    p1 = cosf((float)(start + 1) * div);
                    p2 = cosf((float)(start + 2) * div);
                } else {
                    p0 = sinf((float)start * div);
                    p1 = sinf((float)(start + 1) * div);
                    p2 = sinf((float)(start + 2) * div);
                }
                float* hr = P.h + (size_t)rr * DMODEL;
                float v0 = cm + p0, v1 = cs + p1, v2 = acc + p2;
                hr[c] = v0; hr[c + 256] = v1; hr[c + 512] = v2;
                bf16* hb = P.hB + (size_t)rr * DMODEL;
                hb[c] = (bf16)v0; hb[c + 256] = (bf16)v1; hb[c + 512] = (bf16)v2;
            }
            __syncthreads();
        }
    }
}

// ---------------- bf16 MFMA GEMM stage: tile 80x64, 5 waves -----------------
// Same verified fragment mapping as the 64x64/4-wave version; wave w owns
// rows m0+w*16..+15 (w in 0..4), A staged by all 320 threads (sr=tid>>2 in
// 0..79), B staged by tid<256 (rows 0..63).  M fixed at 640 (8 row tiles).
// EPI: 0 = QKV (elu+1 on Q,K cols, bf16 out); 1 = bias+resid f32 out;
//      2 = bias+relu bf16 out.
template <int EPI>
__device__ void gemm_stage(char* smem,
        const bf16* __restrict__ A, const bf16* __restrict__ Bt,
        const float* __restrict__ bias_q, const float* __restrict__ bias_k,
        const float* __restrict__ bias_v, const float* __restrict__ resid,
        float* __restrict__ outF, bf16* __restrict__ outB, int N, int K) {
    bf16 (*As0)[40] = (bf16(*)[40])(smem);           // 80*40*2 = 6400
    bf16 (*As1)[40] = (bf16(*)[40])(smem + 6400);
    bf16 (*Bs0)[40] = (bf16(*)[40])(smem + 12800);   // 64*40*2 = 5120
    bf16 (*Bs1)[40] = (bf16(*)[40])(smem + 17920);
    int tid = threadIdx.x;
    int w = tid >> 6, l = tid & 63;
    int lm = l & 15, lq = l >> 4;
    int sr = tid >> 2;          // 0..79
    int sk = (tid & 3) * 8;
    int ntiles = 8 * (N / 64);
#pragma unroll 1
    for (int tile = blockIdx.x; tile < ntiles; tile += gridDim.x) {
        int m0 = (tile & 7) * 80;
        int n0 = (tile >> 3) * 64;
        const bf16* Arow = &A[(size_t)(m0 + sr) * K + sk];
        const bf16* Brow = &Bt[(size_t)(n0 + (sr & 63)) * K + sk];
        f32x4 acc[4] = {};
        uint4 a0 = *(const uint4*)(Arow);
        uint4 a1 = *(const uint4*)(Arow + 32);
        uint4 b0 = {}, b1 = {};
        if (tid < 256) { b0 = *(const uint4*)(Brow); b1 = *(const uint4*)(Brow + 32); }
        for (int k0 = 0; k0 < K; k0 += 64) {
            __syncthreads();
            *(uint4*)&As0[sr][sk] = a0;
            *(uint4*)&As1[sr][sk] = a1;
            if (tid < 256) {
                *(uint4*)&Bs0[sr][sk] = b0;
                *(uint4*)&Bs1[sr][sk] = b1;
            }
            __syncthreads();
            int k2 = k0 + 64; if (k2 >= K) k2 = 0;   // tail: harmless re-read
            a0 = *(const uint4*)(Arow + k2);
            a1 = *(const uint4*)(Arow + k2 + 32);
            if (tid < 256) {
                b0 = *(const uint4*)(Brow + k2);
                b1 = *(const uint4*)(Brow + k2 + 32);
            }
            bf16x8 af0 = *(bf16x8*)&As0[w * 16 + lm][lq * 8];
            bf16x8 af1 = *(bf16x8*)&As1[w * 16 + lm][lq * 8];
#pragma unroll
            for (int nb = 0; nb < 4; nb++) {
                bf16x8 bfr = *(bf16x8*)&Bs0[nb * 16 + lm][lq * 8];
                acc[nb] = __builtin_amdgcn_mfma_f32_16x16x32_bf16(af0, bfr, acc[nb], 0, 0, 0);
            }
#pragma unroll
            for (int nb = 0; nb < 4; nb++) {
                bf16x8 bfr = *(bf16x8*)&Bs1[nb * 16 + lm][lq * 8];
                acc[nb] = __builtin_amdgcn_mfma_f32_16x16x32_bf16(af1, bfr, acc[nb], 0, 0, 0);
            }
        }
#pragma unroll
        for (int nb = 0; nb < 4; nb++) {
            int col = n0 + nb * 16 + lm;
            float bia; bool do_elu = false;
            if (EPI == 0) {
                if (col < 768)       { bia = bias_q[col];        do_elu = true; }
                else if (col < 1536) { bia = bias_k[col - 768];  do_elu = true; }
                else                 { bia = bias_v[col - 1536]; }
            } else {
                bia = bias_q[col];
            }
#pragma unroll
            for (int r = 0; r < 4; r++) {
                int row = m0 + w * 16 + lq * 4 + r;
                float v = acc[nb][r] + bia;
                if (EPI == 0) {
                    if (do_elu) v = (v > 0.0f) ? (v + 1.0f) : expf(v);
                    outB[(size_t)row * N + col] = (bf16)v;
                } else if (EPI == 1) {
                    v += resid[(size_t)row * N + col];
                    outF[(size_t)row * N + col] = v;
                } else {
                    v = fmaxf(v, 0.0f);
                    outB[(size_t)row * N + col] = (bf16)v;
                }
            }
        }
    }
}

// ---------------- causal linear attention (one (b,h) job per block) ---------
__device__ void attn_stage(char* smem, const bf16* __restrict__ qkvB,
                           bf16* __restrict__ att) {
    bf16* Qs = (bf16*)smem;            // [80][200]
    bf16* Ks = (bf16*)(smem + 32000);  // [80][200]
    bf16* Aij = (bf16*)smem;           // [80][104]  (overlays Qs after phase 1)
    bf16* VT = (bf16*)(smem + 16640);  // [192][104] (overlays Ks)
    int bb = blockIdx.x >> 2, hd = blockIdx.x & 3;
    int tid = threadIdx.x;
    int w = tid >> 6, l = tid & 63;
    int lm = l & 15, lq = l >> 4;

    uint4 vreg[6];
#pragma unroll
    for (int u = 0; u < 6; u++) {
        int c = tid + 320 * u;
        int t = c / 24, cc = c % 24;
        int d0 = cc * 8;
        size_t g = (size_t)(t * 8 + bb) * NQKV + hd * DH + d0;
        uint4 qv = *(const uint4*)&qkvB[g];
        uint4 kv = *(const uint4*)&qkvB[g + 768];
        vreg[u]  = *(const uint4*)&qkvB[g + 1536];
        *(uint4*)&Qs[t * 200 + d0] = qv;
        *(uint4*)&Ks[t * 200 + d0] = kv;
    }
    __syncthreads();

    f32x4 acc[5] = {};
#pragma unroll
    for (int k0 = 0; k0 < 192; k0 += 32) {
        bf16x8 af = *(bf16x8*)&Qs[(w * 16 + lm) * 200 + lq * 8 + k0];
#pragma unroll
        for (int nb = 0; nb < 5; nb++) {
            bf16x8 bfr = *(bf16x8*)&Ks[(nb * 16 + lm) * 200 + lq * 8 + k0];
            acc[nb] = __builtin_amdgcn_mfma_f32_16x16x32_bf16(af, bfr, acc[nb], 0, 0, 0);
        }
    }
    float mval[5][4];
    float rs[4] = {0.f, 0.f, 0.f, 0.f};
#pragma unroll
    for (int nb = 0; nb < 5; nb++)
#pragma unroll
        for (int r = 0; r < 4; r++) {
            int t = w * 16 + lq * 4 + r, tau = nb * 16 + lm;
            float v = (tau <= t) ? acc[nb][r] : 0.0f;
            mval[nb][r] = v;
            rs[r] += v;
        }
#pragma unroll
    for (int mk = 1; mk < 16; mk <<= 1)
#pragma unroll
        for (int r = 0; r < 4; r++) rs[r] += __shfl_xor(rs[r], mk, 64);
    float inv[4];
#pragma unroll
    for (int r = 0; r < 4; r++) inv[r] = 1.0f / (rs[r] + 1e-6f);

    __syncthreads();

#pragma unroll
    for (int nb = 0; nb < 5; nb++)
#pragma unroll
        for (int r = 0; r < 4; r++)
            Aij[(w * 16 + lq * 4 + r) * 104 + nb * 16 + lm] = (bf16)mval[nb][r];
    *(uint2*)&Aij[(tid >> 2) * 104 + 80 + (tid & 3) * 4] = make_uint2(0u, 0u);
#pragma unroll
    for (int u = 0; u < 6; u++) {
        int c = tid + 320 * u;
        int t = c / 24, cc = c % 24;
        int d0 = cc * 8;
        bf16 tmp8[8];
        *(uint4*)tmp8 = vreg[u];
#pragma unroll
        for (int j = 0; j < 8; j++) VT[(d0 + j) * 104 + t] = tmp8[j];
    }
    if (tid < 192) {
        *(uint4*)&VT[tid * 104 + 80] = make_uint4(0u, 0u, 0u, 0u);
        *(uint4*)&VT[tid * 104 + 88] = make_uint4(0u, 0u, 0u, 0u);
    }
    __syncthreads();

#pragma unroll 1
    for (int nc = 0; nc < 12; nc++) {
        f32x4 a2 = {};
#pragma unroll
        for (int k0 = 0; k0 < 96; k0 += 32) {
            bf16x8 af = *(bf16x8*)&Aij[(w * 16 + lm) * 104 + lq * 8 + k0];
            bf16x8 bfr = *(bf16x8*)&VT[(nc * 16 + lm) * 104 + lq * 8 + k0];
            a2 = __builtin_amdgcn_mfma_f32_16x16x32_bf16(af, bfr, a2, 0, 0, 0);
        }
#pragma unroll
        for (int r = 0; r < 4; r++) {
            int t = w * 16 + lq * 4 + r;
            att[(size_t)(t * 8 + bb) * DMODEL + hd * DH + nc * 16 + lm] =
                (bf16)(a2[r] * inv[r]);
        }
    }
}

// ---------------- row LayerNorm over 768: one wave per row ------------------
__device__ void ln_stage(const float* __restrict__ in, float* __restrict__ outF,
        bf16* __restrict__ outB,
        const float* __restrict__ g, const float* __restrict__ b) {
    int wave = threadIdx.x >> 6, lane = threadIdx.x & 63;
#pragma unroll 1
    for (int row = blockIdx.x * 5 + wave; row < NROWS; row += gridDim.x * 5) {
        const float* xr = in + (size_t)row * DMODEL;
        float4 v[3];
        float s = 0.0f;
#pragma unroll
        for (int j = 0; j < 3; j++) {
            v[j] = *(const float4*)&xr[lane * 4 + 256 * j];
            s += v[j].x + v[j].y + v[j].z + v[j].w;
        }
#pragma unroll
        for (int mk = 1; mk < 64; mk <<= 1) s += __shfl_xor(s, mk, 64);
        float m = s * (1.0f / 768.0f);
        float sq = 0.0f;
#pragma unroll
        for (int j = 0; j < 3; j++) {
            v[j].x -= m; v[j].y -= m; v[j].z -= m; v[j].w -= m;
            sq += v[j].x * v[j].x + v[j].y * v[j].y + v[j].z * v[j].z + v[j].w * v[j].w;
        }
#pragma unroll
        for (int mk = 1; mk < 64; mk <<= 1) sq += __shfl_xor(sq, mk, 64);
        float r = rsqrtf(sq * (1.0f / 768.0f) + 1e-5f);
        float* orow = outF + (size_t)row * DMODEL;
        bf16* brow = outB + (size_t)row * DMODEL;
#pragma unroll
        for (int j = 0; j < 3; j++) {
            int c = lane * 4 + 256 * j;
            float4 gg = *(const float4*)&g[c];
            float4 bbv = *(const float4*)&b[c];
            float o0 = v[j].x * r * gg.x + bbv.x;
            float o1 = v[j].y * r * gg.y + bbv.y;
            float o2 = v[j].z * r * gg.z + bbv.z;
            float o3 = v[j].w * r * gg.w + bbv.w;
            *(float4*)&orow[c] = make_float4(o0, o1, o2, o3);
            bf16 tmp4[4] = {(bf16)o0, (bf16)o1, (bf16)o2, (bf16)o3};
            *(uint2*)&brow[c] = *(uint2*)tmp4;
        }
    }
}

// ---------------- final LN + output gather (blocks 0..47) -------------------
__device__ __forceinline__ float block_reduce_sum5(float v, float* sm) {
#pragma unroll
    for (int off = 32; off > 0; off >>= 1) v += __shfl_down(v, off, 64);
    int lane = threadIdx.x & 63, wid = threadIdx.x >> 6;
    __syncthreads();
    if (lane == 0) sm[wid] = v;
    __syncthreads();
    return sm[0] + sm[1] + sm[2] + sm[3] + sm[4];
}

__device__ void final_stage(char* smem, const float* __restrict__ hbuf,
        const int* __restrict__ act_ts, const float* __restrict__ g,
        const float* __restrict__ bb, float* __restrict__ out) {
    float* sm = (float*)smem;
    int ba = blockIdx.x;
    int b = ba / NA;
    int ts = act_ts[ba];
    int t = ts - 1; if (t < 0) t = 0;
    const float* xr = hbuf + (size_t)(t * 8 + b) * DMODEL;
    int c = threadIdx.x;
    float x0 = 0.f, x1 = 0.f, x2 = 0.f;
    if (c < 256) { x0 = xr[c]; x1 = xr[c + 256]; x2 = xr[c + 512]; }
    float m = block_reduce_sum5(x0 + x1 + x2, sm) * (1.0f / 768.0f);
    float d0 = x0 - m, d1 = x1 - m, d2 = x2 - m;
    float contrib = (c < 256) ? (d0 * d0 + d1 * d1 + d2 * d2) : 0.f;
    float v = block_reduce_sum5(contrib, sm) * (1.0f / 768.0f);
    float r = rsqrtf(v + 1e-5f);
    if (c < 256) {
        out[ba * 256 + c]            = d0 * r * g[c] + bb[c];
        out[48 * 256 + ba * 256 + c] = d1 * r * g[c + 256] + bb[c + 256];
    }
}

// ---------------- the megakernel --------------------------------------------
__global__ __launch_bounds__(NTHREADS) void mega_k(MegaP P) {
    __shared__ __attribute__((aligned(16))) char smem[64000];
    int nb = gridDim.x;
    int bno = 0;
    prep_stage(smem, P);
    bno += nb; gbar(P.bar, bno);
#pragma unroll 1
    for (int l = 0; l < 4; l++) {
        gemm_stage<0>(smem, P.hB, P.qkvT + (size_t)l * NQKV * DMODEL,
                      P.bq + l * DMODEL, P.bk + l * DMODEL, P.bv + l * DMODEL,
                      nullptr, nullptr, P.qkvB, NQKV, DMODEL);
        bno += nb; gbar(P.bar, bno);
        if (blockIdx.x < 32) attn_stage(smem, P.qkvB, P.attB);
        bno += nb; gbar(P.bar, bno);
        gemm_stage<1>(smem, P.attB, P.woT + (size_t)l * DMODEL * DMODEL,
                      P.bo + l * DMODEL, nullptr, nullptr, P.h, P.tmp, nullptr,
                      DMODEL, DMODEL);
        bno += nb; gbar(P.bar, bno);
        ln_stage(P.tmp, P.h1, P.h1B, P.ln1_g + l * DMODEL, P.ln1_b + l * DMODEL);
        bno += nb; gbar(P.bar, bno);
        gemm_stage<2>(smem, P.h1B, P.w1T + (size_t)l * FFD * DMODEL,
                      P.b1 + l * FFD, nullptr, nullptr, nullptr, nullptr, P.ffn1B,
                      FFD, DMODEL);
        bno += nb; gbar(P.bar, bno);
        gemm_stage<1>(smem, P.ffn1B, P.w2T + (size_t)l * DMODEL * FFD,
                      P.b2 + l * DMODEL, nullptr, nullptr, P.h1, P.tmp, nullptr,
                      DMODEL, FFD);
        bno += nb; gbar(P.bar, bno);
        ln_stage(P.tmp, P.h, P.hB, P.ln2_g + l * DMODEL, P.ln2_b + l * DMODEL);
        bno += nb; gbar(P.bar, bno);
    }
    if (blockIdx.x < 48)
        final_stage(smem, P.h, P.act_ts, P.lnf_g, P.lnf_b, P.out);
}

extern "C" void kernel_launch(void* const* d_in, const int* in_sizes, int n_in,
                              void* d_out, int out_size, void* d_ws, size_t ws_size,
                              hipStream_t stream) {
    MegaP P;
    P.x       = (const float*)d_in[0];
    P.y       = (const int*)d_in[1];
    P.ind_map = (const int*)d_in[2];
    P.act_ts  = (const int*)d_in[3];
    P.skel_W  = (const float*)d_in[4];
    P.skel_b  = (const float*)d_in[5];
    P.muQ     = (const float*)d_in[6];
    P.sigQ    = (const float*)d_in[7];
    P.Wq = (const float*)d_in[8];   P.bq = (const float*)d_in[9];
    P.Wk = (const float*)d_in[10];  P.bk = (const float*)d_in[11];
    P.Wv = (const float*)d_in[12];  P.bv = (const float*)d_in[13];
    P.Wo = (const float*)d_in[14];  P.bo = (const float*)d_in[15];
    P.W1 = (const float*)d_in[16];  P.b1 = (const float*)d_in[17];
    P.W2 = (const float*)d_in[18];  P.b2 = (const float*)d_in[19];
    P.ln1_g = (const float*)d_in[20]; P.ln1_b = (const float*)d_in[21];
    P.ln2_g = (const float*)d_in[22]; P.ln2_b = (const float*)d_in[23];
    P.lnf_g = (const float*)d_in[24]; P.lnf_b = (const float*)d_in[25];
    P.out = (float*)d_out;

    // ---- workspace layout (all 16B aligned) ----
    char* p = (char*)d_ws;
    P.bar = (int*)p; p += 64;
    const size_t R = (size_t)NROWS * DMODEL;
    P.h    = (float*)p; p += R * 4;
    P.h1   = (float*)p; p += R * 4;
    P.tmp  = (float*)p; p += R * 4;
    P.qkvB  = (bf16*)p; p += (size_t)NROWS * NQKV * 2;
    P.hB    = (bf16*)p; p += R * 2;
    P.h1B   = (bf16*)p; p += R * 2;
    P.attB  = (bf16*)p; p += R * 2;
    P.ffn1B = (bf16*)p; p += (size_t)NROWS * FFD * 2;
    P.qkvT  = (bf16*)p; p += (size_t)4 * NQKV * DMODEL * 2;
    P.woT   = (bf16*)p; p += (size_t)4 * DMODEL * DMODEL * 2;
    P.w1T   = (bf16*)p; p += (size_t)4 * FFD * DMODEL * 2;
    P.w2T   = (bf16*)p; p += (size_t)4 * DMODEL * FFD * 2;

    hipMemsetAsync(P.bar, 0, 64, stream);
    void* args[] = { (void*)&P };
    hipLaunchCooperativeKernel(reinterpret_cast<const void*>(mega_k),
                               dim3(NBLOCKS), dim3(NTHREADS), args, 0, stream);
}

// Round 3
// 722.667 us; speedup vs baseline: 1.3537x; 1.3537x over previous
//
#include <hip/hip_runtime.h>
#include <math.h>

// ---- problem constants ----
#define TT 80
#define BS 8
#define NA 6
#define DMODEL 768
#define DH 192
#define FFD 1024
#define NROWS (TT*BS)   // 640
#define NQKV (3*DMODEL) // 2304
#define NTHREADS 320    // 5 waves
#define NBLOCKS 256     // 1 block/CU -> trivially co-resident

typedef __bf16 bf16;
typedef __bf16 bf16x8 __attribute__((ext_vector_type(8)));
typedef float  f32x4  __attribute__((ext_vector_type(4)));

struct MegaP {
    const float *x; const int *y; const int *ind_map; const int *act_ts;
    const float *skel_W, *skel_b, *muQ, *sigQ;
    const float *Wq, *bq, *Wk, *bk, *Wv, *bv, *Wo, *bo, *W1, *b1, *W2, *b2;
    const float *ln1_g, *ln1_b, *ln2_g, *ln2_b, *lnf_g, *lnf_b;
    float *out;
    float *h, *h1, *tmp;
    bf16 *qkvB, *hB, *h1B, *attB, *ffn1B, *qkvT, *woT, *w1T, *w2T;
    int *bar;
};

// ---------------- cache-bypass loads for cross-stage activations ------------
// Agent-scope relaxed atomic loads read at the coherence point (sc0 sc1):
// no stale L1/L2 lines can be served, so the barrier needs NO cache
// invalidate on the reader side.  Weights use normal cached loads (their
// addresses are written once in prep, flushed at the prep barrier, never
// stale afterwards) so L2 stays warm across all stages.
__device__ __forceinline__ uint4 ld_bypass16(const void* p) {
    const unsigned long long* q = (const unsigned long long*)p;
    unsigned long long lo = __hip_atomic_load(q,     __ATOMIC_RELAXED, __HIP_MEMORY_SCOPE_AGENT);
    unsigned long long hi = __hip_atomic_load(q + 1, __ATOMIC_RELAXED, __HIP_MEMORY_SCOPE_AGENT);
    uint4 r;
    r.x = (unsigned)lo; r.y = (unsigned)(lo >> 32);
    r.z = (unsigned)hi; r.w = (unsigned)(hi >> 32);
    return r;
}
__device__ __forceinline__ float ld_bypassf(const float* p) {
    unsigned u = __hip_atomic_load((const unsigned*)p, __ATOMIC_RELAXED, __HIP_MEMORY_SCOPE_AGENT);
    return __uint_as_float(u);
}
__device__ __forceinline__ float4 ld_bypassf4(const float* p) {
    uint4 u = ld_bypass16(p);
    return make_float4(__uint_as_float(u.x), __uint_as_float(u.y),
                       __uint_as_float(u.z), __uint_as_float(u.w));
}

// ---------------- hierarchical grid barrier ---------------------------------
// 8 group counters (128B apart; 32 arrivals each) + root (8 arrivals).
// Release on each arrive flushes the arriving XCD's dirty L2 lines (compiler
// emits wbl2 for agent-release).  NO invalidate on exit: readers use bypass
// loads for activations; weights are never stale.  Root poll with backoff.
__device__ __forceinline__ void gbar(int* barmem, int s) {
    __syncthreads();
    if (threadIdx.x == 0) {
        int g = blockIdx.x & 7;
        int* gc = barmem + g * 32;
        int* rc = barmem + 8 * 32;
        int prev = __hip_atomic_fetch_add(gc, 1, __ATOMIC_RELEASE, __HIP_MEMORY_SCOPE_AGENT);
        if (prev == s * 32 + 31)
            __hip_atomic_fetch_add(rc, 1, __ATOMIC_RELEASE, __HIP_MEMORY_SCOPE_AGENT);
        while (__hip_atomic_load(rc, __ATOMIC_RELAXED, __HIP_MEMORY_SCOPE_AGENT) < (s + 1) * 8)
            __builtin_amdgcn_s_sleep(8);
        __atomic_signal_fence(__ATOMIC_ACQUIRE);
    }
    __syncthreads();
}

// ---------------- stage 0: weight transpose->bf16 + embedding ---------------
struct TJob { const float* src; bf16* dst; int ldsrc, Kd, n0, k0; };

__device__ __forceinline__ TJob tjob_decode(const MegaP& P, int job) {
    TJob J;
    int l = job / 3840, r = job % 3840;
    if (r < 1728) {                             // QKV: K=768, N=2304
        int kt = r % 24, nt = r / 24;
        J.k0 = kt * 32; J.n0 = nt * 32; J.Kd = 768; J.ldsrc = 768;
        J.dst = P.qkvT + (size_t)l * NQKV * DMODEL;
        if (J.n0 < 768)       { J.src = P.Wq + (size_t)l * 589824 + J.n0; }
        else if (J.n0 < 1536) { J.src = P.Wk + (size_t)l * 589824 + (J.n0 - 768); }
        else                  { J.src = P.Wv + (size_t)l * 589824 + (J.n0 - 1536); }
    } else if (r < 2304) {                      // Wo: 768x768
        int r2 = r - 1728; int kt = r2 % 24, nt = r2 / 24;
        J.k0 = kt * 32; J.n0 = nt * 32; J.Kd = 768; J.ldsrc = 768;
        J.src = P.Wo + (size_t)l * 589824 + J.n0;
        J.dst = P.woT + (size_t)l * 589824;
    } else if (r < 3072) {                      // W1: K=768, N=1024
        int r2 = r - 2304; int kt = r2 % 24, nt = r2 / 24;
        J.k0 = kt * 32; J.n0 = nt * 32; J.Kd = 768; J.ldsrc = 1024;
        J.src = P.W1 + (size_t)l * 786432 + J.n0;
        J.dst = P.w1T + (size_t)l * 786432;
    } else {                                    // W2: K=1024, N=768
        int r2 = r - 3072; int kt = r2 % 32, nt = r2 / 32;
        J.k0 = kt * 32; J.n0 = nt * 32; J.Kd = 1024; J.ldsrc = 768;
        J.src = P.W2 + (size_t)l * 786432 + J.n0;
        J.dst = P.w2T + (size_t)l * 786432;
    }
    return J;
}

__device__ void prep_stage(char* smem, const MegaP& P) {
    float (*tile)[32][33] = (float(*)[32][33])smem;   // 4 x 4224 B = 16896 B
    float* xrow = (float*)(smem + 20480);             // 600 B
    int tid = threadIdx.x;
    int tx = tid & 31, ty = (tid >> 5) & 7;
    // --- transposes: 15360 jobs, 4 per block-iteration (exactly 15 iters) ---
#pragma unroll 1
    for (int j0 = blockIdx.x * 4; j0 < 15360; j0 += gridDim.x * 4) {
        if (tid < 256) {
#pragma unroll
            for (int t = 0; t < 4; t++) {
                TJob J = tjob_decode(P, j0 + t);
#pragma unroll
                for (int i = 0; i < 4; i++) {
                    int rr = ty + 8 * i;
                    tile[t][rr][tx] = J.src[(size_t)(J.k0 + rr) * J.ldsrc + tx];
                }
            }
        }
        __syncthreads();
        if (tid < 256) {
#pragma unroll
            for (int t = 0; t < 4; t++) {
                TJob J = tjob_decode(P, j0 + t);
#pragma unroll
                for (int i = 0; i < 4; i++) {
                    int rr = ty + 8 * i;
                    J.dst[(size_t)(J.n0 + rr) * J.Kd + J.k0 + tx] = (bf16)tile[t][tx][rr];
                }
            }
        }
        __syncthreads();
    }
    // --- embedding: 640 jobs ---
#pragma unroll 1
    for (int rr = blockIdx.x; rr < 640; rr += gridDim.x) {
        int t = rr >> 3, b = rr & 7;
        int c = tid;
        if (c < 150) xrow[c] = P.x[(b * 150 + c) * TT + t];
        __syncthreads();
        if (c < 256) {
            float acc = P.skel_b[c];
            for (int jf = 0; jf < 150; jf++) acc += xrow[jf] * P.skel_W[jf * 256 + c];
            int ind_t = P.ind_map[t * 8 + b];
            int yb = P.y[b * NA + ind_t];
            float cm = P.muQ[yb * 256 + c];
            float cs = P.sigQ[yb * 256 + c];
            int start = (t == 0) ? 0 : (t + 2);
            float div = expf((float)(c & ~1) * (-9.210340371976184f / 256.0f));
            float p0, p1, p2;
            if (c & 1) {
                p0 = cosf((float)start * div);
                p1 = cosf((float)(start + 1) * div);
                p2 = cosf((float)(start + 2) * div);
            } else {
                p0 = sinf((float)start * div);
                p1 = sinf((float)(start + 1) * div);
                p2 = sinf((float)(start + 2) * div);
            }
            float* hr = P.h + (size_t)rr * DMODEL;
            float v0 = cm + p0, v1 = cs + p1, v2 = acc + p2;
            hr[c] = v0; hr[c + 256] = v1; hr[c + 512] = v2;
            bf16* hb = P.hB + (size_t)rr * DMODEL;
            hb[c] = (bf16)v0; hb[c + 256] = (bf16)v1; hb[c + 512] = (bf16)v2;
        }
        __syncthreads();
    }
}

// ---------------- bf16 MFMA GEMM stage: tile 80x64, 5 waves -----------------
// A (activations) via bypass loads; Bt (weights) via normal cached loads.
// EPI: 0 = QKV (elu+1 on Q,K cols, bf16 out); 1 = bias+resid f32 out;
//      2 = bias+relu bf16 out.
template <int EPI>
__device__ void gemm_stage(char* smem,
        const bf16* __restrict__ A, const bf16* __restrict__ Bt,
        const float* __restrict__ bias_q, const float* __restrict__ bias_k,
        const float* __restrict__ bias_v, const float* __restrict__ resid,
        float* __restrict__ outF, bf16* __restrict__ outB, int N, int K) {
    bf16 (*As0)[40] = (bf16(*)[40])(smem);           // 80*40*2 = 6400
    bf16 (*As1)[40] = (bf16(*)[40])(smem + 6400);
    bf16 (*Bs0)[40] = (bf16(*)[40])(smem + 12800);   // 64*40*2 = 5120
    bf16 (*Bs1)[40] = (bf16(*)[40])(smem + 17920);
    int tid = threadIdx.x;
    int w = tid >> 6, l = tid & 63;
    int lm = l & 15, lq = l >> 4;
    int sr = tid >> 2;          // 0..79
    int sk = (tid & 3) * 8;
    int ntiles = 8 * (N / 64);
#pragma unroll 1
    for (int tile = blockIdx.x; tile < ntiles; tile += gridDim.x) {
        int m0 = (tile & 7) * 80;
        int n0 = (tile >> 3) * 64;
        const bf16* Arow = &A[(size_t)(m0 + sr) * K + sk];
        const bf16* Brow = &Bt[(size_t)(n0 + (sr & 63)) * K + sk];
        f32x4 acc[4] = {};
        uint4 a0 = ld_bypass16(Arow);
        uint4 a1 = ld_bypass16(Arow + 32);
        uint4 b0 = {}, b1 = {};
        if (tid < 256) { b0 = *(const uint4*)(Brow); b1 = *(const uint4*)(Brow + 32); }
        for (int k0 = 0; k0 < K; k0 += 64) {
            __syncthreads();
            *(uint4*)&As0[sr][sk] = a0;
            *(uint4*)&As1[sr][sk] = a1;
            if (tid < 256) {
                *(uint4*)&Bs0[sr][sk] = b0;
                *(uint4*)&Bs1[sr][sk] = b1;
            }
            __syncthreads();
            int k2 = k0 + 64; if (k2 >= K) k2 = 0;   // tail: harmless re-read
            a0 = ld_bypass16(Arow + k2);
            a1 = ld_bypass16(Arow + k2 + 32);
            if (tid < 256) {
                b0 = *(const uint4*)(Brow + k2);
                b1 = *(const uint4*)(Brow + k2 + 32);
            }
            bf16x8 af0 = *(bf16x8*)&As0[w * 16 + lm][lq * 8];
            bf16x8 af1 = *(bf16x8*)&As1[w * 16 + lm][lq * 8];
#pragma unroll
            for (int nb = 0; nb < 4; nb++) {
                bf16x8 bfr = *(bf16x8*)&Bs0[nb * 16 + lm][lq * 8];
                acc[nb] = __builtin_amdgcn_mfma_f32_16x16x32_bf16(af0, bfr, acc[nb], 0, 0, 0);
            }
#pragma unroll
            for (int nb = 0; nb < 4; nb++) {
                bf16x8 bfr = *(bf16x8*)&Bs1[nb * 16 + lm][lq * 8];
                acc[nb] = __builtin_amdgcn_mfma_f32_16x16x32_bf16(af1, bfr, acc[nb], 0, 0, 0);
            }
        }
#pragma unroll
        for (int nb = 0; nb < 4; nb++) {
            int col = n0 + nb * 16 + lm;
            float bia; bool do_elu = false;
            if (EPI == 0) {
                if (col < 768)       { bia = bias_q[col];        do_elu = true; }
                else if (col < 1536) { bia = bias_k[col - 768];  do_elu = true; }
                else                 { bia = bias_v[col - 1536]; }
            } else {
                bia = bias_q[col];
            }
#pragma unroll
            for (int r = 0; r < 4; r++) {
                int row = m0 + w * 16 + lq * 4 + r;
                float v = acc[nb][r] + bia;
                if (EPI == 0) {
                    if (do_elu) v = (v > 0.0f) ? (v + 1.0f) : expf(v);
                    outB[(size_t)row * N + col] = (bf16)v;
                } else if (EPI == 1) {
                    v += ld_bypassf(&resid[(size_t)row * N + col]);
                    outF[(size_t)row * N + col] = v;
                } else {
                    v = fmaxf(v, 0.0f);
                    outB[(size_t)row * N + col] = (bf16)v;
                }
            }
        }
    }
}

// ---------------- causal linear attention -----------------------------------
// 96 blocks: (b,h) = blockIdx/3, nc-range = (blockIdx%3)*4..+3 (QK^T redone
// per part -- cheap; PV cols split 3x for more CUs).
__device__ void attn_stage(char* smem, const bf16* __restrict__ qkvB,
                           bf16* __restrict__ att) {
    bf16* Qs = (bf16*)smem;            // [80][200]
    bf16* Ks = (bf16*)(smem + 32000);  // [80][200]
    bf16* Aij = (bf16*)smem;           // [80][104]  (overlays Qs after phase 1)
    bf16* VT = (bf16*)(smem + 16640);  // [192][104] (overlays Ks)
    int bh = blockIdx.x / 3, part = blockIdx.x % 3;
    int bb = bh >> 2, hd = bh & 3;
    int tid = threadIdx.x;
    int w = tid >> 6, l = tid & 63;
    int lm = l & 15, lq = l >> 4;

    uint4 vreg[6];
#pragma unroll
    for (int u = 0; u < 6; u++) {
        int c = tid + 320 * u;
        int t = c / 24, cc = c % 24;
        int d0 = cc * 8;
        size_t g = (size_t)(t * 8 + bb) * NQKV + hd * DH + d0;
        uint4 qv = ld_bypass16(&qkvB[g]);
        uint4 kv = ld_bypass16(&qkvB[g + 768]);
        vreg[u]  = ld_bypass16(&qkvB[g + 1536]);
        *(uint4*)&Qs[t * 200 + d0] = qv;
        *(uint4*)&Ks[t * 200 + d0] = kv;
    }
    __syncthreads();

    f32x4 acc[5] = {};
#pragma unroll
    for (int k0 = 0; k0 < 192; k0 += 32) {
        bf16x8 af = *(bf16x8*)&Qs[(w * 16 + lm) * 200 + lq * 8 + k0];
#pragma unroll
        for (int nb = 0; nb < 5; nb++) {
            bf16x8 bfr = *(bf16x8*)&Ks[(nb * 16 + lm) * 200 + lq * 8 + k0];
            acc[nb] = __builtin_amdgcn_mfma_f32_16x16x32_bf16(af, bfr, acc[nb], 0, 0, 0);
        }
    }
    float mval[5][4];
    float rs[4] = {0.f, 0.f, 0.f, 0.f};
#pragma unroll
    for (int nb = 0; nb < 5; nb++)
#pragma unroll
        for (int r = 0; r < 4; r++) {
            int t = w * 16 + lq * 4 + r, tau = nb * 16 + lm;
            float v = (tau <= t) ? acc[nb][r] : 0.0f;
            mval[nb][r] = v;
            rs[r] += v;
        }
#pragma unroll
    for (int mk = 1; mk < 16; mk <<= 1)
#pragma unroll
        for (int r = 0; r < 4; r++) rs[r] += __shfl_xor(rs[r], mk, 64);
    float inv[4];
#pragma unroll
    for (int r = 0; r < 4; r++) inv[r] = 1.0f / (rs[r] + 1e-6f);

    __syncthreads();

#pragma unroll
    for (int nb = 0; nb < 5; nb++)
#pragma unroll
        for (int r = 0; r < 4; r++)
            Aij[(w * 16 + lq * 4 + r) * 104 + nb * 16 + lm] = (bf16)mval[nb][r];
    *(uint2*)&Aij[(tid >> 2) * 104 + 80 + (tid & 3) * 4] = make_uint2(0u, 0u);
#pragma unroll
    for (int u = 0; u < 6; u++) {
        int c = tid + 320 * u;
        int t = c / 24, cc = c % 24;
        int d0 = cc * 8;
        bf16 tmp8[8];
        *(uint4*)tmp8 = vreg[u];
#pragma unroll
        for (int j = 0; j < 8; j++) VT[(d0 + j) * 104 + t] = tmp8[j];
    }
    if (tid < 192) {
        *(uint4*)&VT[tid * 104 + 80] = make_uint4(0u, 0u, 0u, 0u);
        *(uint4*)&VT[tid * 104 + 88] = make_uint4(0u, 0u, 0u, 0u);
    }
    __syncthreads();

#pragma unroll 1
    for (int nc = part * 4; nc < part * 4 + 4; nc++) {
        f32x4 a2 = {};
#pragma unroll
        for (int k0 = 0; k0 < 96; k0 += 32) {
            bf16x8 af = *(bf16x8*)&Aij[(w * 16 + lm) * 104 + lq * 8 + k0];
            bf16x8 bfr = *(bf16x8*)&VT[(nc * 16 + lm) * 104 + lq * 8 + k0];
            a2 = __builtin_amdgcn_mfma_f32_16x16x32_bf16(af, bfr, a2, 0, 0, 0);
        }
#pragma unroll
        for (int r = 0; r < 4; r++) {
            int t = w * 16 + lq * 4 + r;
            att[(size_t)(t * 8 + bb) * DMODEL + hd * DH + nc * 16 + lm] =
                (bf16)(a2[r] * inv[r]);
        }
    }
}

// ---------------- row LayerNorm over 768: one wave per row ------------------
__device__ void ln_stage(const float* __restrict__ in, float* __restrict__ outF,
        bf16* __restrict__ outB,
        const float* __restrict__ g, const float* __restrict__ b) {
    int wave = threadIdx.x >> 6, lane = threadIdx.x & 63;
#pragma unroll 1
    for (int row = blockIdx.x * 5 + wave; row < NROWS; row += gridDim.x * 5) {
        const float* xr = in + (size_t)row * DMODEL;
        float4 v[3];
        float s = 0.0f;
#pragma unroll
        for (int j = 0; j < 3; j++) {
            v[j] = ld_bypassf4(&xr[lane * 4 + 256 * j]);
            s += v[j].x + v[j].y + v[j].z + v[j].w;
        }
#pragma unroll
        for (int mk = 1; mk < 64; mk <<= 1) s += __shfl_xor(s, mk, 64);
        float m = s * (1.0f / 768.0f);
        float sq = 0.0f;
#pragma unroll
        for (int j = 0; j < 3; j++) {
            v[j].x -= m; v[j].y -= m; v[j].z -= m; v[j].w -= m;
            sq += v[j].x * v[j].x + v[j].y * v[j].y + v[j].z * v[j].z + v[j].w * v[j].w;
        }
#pragma unroll
        for (int mk = 1; mk < 64; mk <<= 1) sq += __shfl_xor(sq, mk, 64);
        float r = rsqrtf(sq * (1.0f / 768.0f) + 1e-5f);
        float* orow = outF + (size_t)row * DMODEL;
        bf16* brow = outB + (size_t)row * DMODEL;
#pragma unroll
        for (int j = 0; j < 3; j++) {
            int c = lane * 4 + 256 * j;
            float4 gg = *(const float4*)&g[c];
            float4 bbv = *(const float4*)&b[c];
            float o0 = v[j].x * r * gg.x + bbv.x;
            float o1 = v[j].y * r * gg.y + bbv.y;
            float o2 = v[j].z * r * gg.z + bbv.z;
            float o3 = v[j].w * r * gg.w + bbv.w;
            *(float4*)&orow[c] = make_float4(o0, o1, o2, o3);
            bf16 tmp4[4] = {(bf16)o0, (bf16)o1, (bf16)o2, (bf16)o3};
            *(uint2*)&brow[c] = *(uint2*)tmp4;
        }
    }
}

// ---------------- final LN + output gather (blocks 0..47) -------------------
__device__ __forceinline__ float block_reduce_sum5(float v, float* sm) {
#pragma unroll
    for (int off = 32; off > 0; off >>= 1) v += __shfl_down(v, off, 64);
    int lane = threadIdx.x & 63, wid = threadIdx.x >> 6;
    __syncthreads();
    if (lane == 0) sm[wid] = v;
    __syncthreads();
    return sm[0] + sm[1] + sm[2] + sm[3] + sm[4];
}

__device__ void final_stage(char* smem, const float* __restrict__ hbuf,
        const int* __restrict__ act_ts, const float* __restrict__ g,
        const float* __restrict__ bb, float* __restrict__ out) {
    float* sm = (float*)smem;
    int ba = blockIdx.x;
    int b = ba / NA;
    int ts = act_ts[ba];
    int t = ts - 1; if (t < 0) t = 0;
    const float* xr = hbuf + (size_t)(t * 8 + b) * DMODEL;
    int c = threadIdx.x;
    float x0 = 0.f, x1 = 0.f, x2 = 0.f;
    if (c < 256) {
        x0 = ld_bypassf(&xr[c]);
        x1 = ld_bypassf(&xr[c + 256]);
        x2 = ld_bypassf(&xr[c + 512]);
    }
    float m = block_reduce_sum5(x0 + x1 + x2, sm) * (1.0f / 768.0f);
    float d0 = x0 - m, d1 = x1 - m, d2 = x2 - m;
    float contrib = (c < 256) ? (d0 * d0 + d1 * d1 + d2 * d2) : 0.f;
    float v = block_reduce_sum5(contrib, sm) * (1.0f / 768.0f);
    float r = rsqrtf(v + 1e-5f);
    if (c < 256) {
        out[ba * 256 + c]            = d0 * r * g[c] + bb[c];
        out[48 * 256 + ba * 256 + c] = d1 * r * g[c + 256] + bb[c + 256];
    }
}

// ---------------- the megakernel --------------------------------------------
__global__ __launch_bounds__(NTHREADS) void mega_k(MegaP P) {
    __shared__ __attribute__((aligned(16))) char smem[64000];
    int s = 0;
    prep_stage(smem, P);
    gbar(P.bar, s++);
#pragma unroll 1
    for (int l = 0; l < 4; l++) {
        gemm_stage<0>(smem, P.hB, P.qkvT + (size_t)l * NQKV * DMODEL,
                      P.bq + l * DMODEL, P.bk + l * DMODEL, P.bv + l * DMODEL,
                      nullptr, nullptr, P.qkvB, NQKV, DMODEL);
        gbar(P.bar, s++);
        if (blockIdx.x < 96) attn_stage(smem, P.qkvB, P.attB);
        gbar(P.bar, s++);
        gemm_stage<1>(smem, P.attB, P.woT + (size_t)l * DMODEL * DMODEL,
                      P.bo + l * DMODEL, nullptr, nullptr, P.h, P.tmp, nullptr,
                      DMODEL, DMODEL);
        gbar(P.bar, s++);
        ln_stage(P.tmp, P.h1, P.h1B, P.ln1_g + l * DMODEL, P.ln1_b + l * DMODEL);
        gbar(P.bar, s++);
        gemm_stage<2>(smem, P.h1B, P.w1T + (size_t)l * FFD * DMODEL,
                      P.b1 + l * FFD, nullptr, nullptr, nullptr, nullptr, P.ffn1B,
                      FFD, DMODEL);
        gbar(P.bar, s++);
        gemm_stage<1>(smem, P.ffn1B, P.w2T + (size_t)l * DMODEL * FFD,
                      P.b2 + l * DMODEL, nullptr, nullptr, P.h1, P.tmp, nullptr,
                      DMODEL, FFD);
        gbar(P.bar, s++);
        ln_stage(P.tmp, P.h, P.hB, P.ln2_g + l * DMODEL, P.ln2_b + l * DMODEL);
        gbar(P.bar, s++);
    }
    if (blockIdx.x < 48)
        final_stage(smem, P.h, P.act_ts, P.lnf_g, P.lnf_b, P.out);
}

extern "C" void kernel_launch(void* const* d_in, const int* in_sizes, int n_in,
                              void* d_out, int out_size, void* d_ws, size_t ws_size,
                              hipStream_t stream) {
    MegaP P;
    P.x       = (const float*)d_in[0];
    P.y       = (const int*)d_in[1];
    P.ind_map = (const int*)d_in[2];
    P.act_ts  = (const int*)d_in[3];
    P.skel_W  = (const float*)d_in[4];
    P.skel_b  = (const float*)d_in[5];
    P.muQ     = (const float*)d_in[6];
    P.sigQ    = (const float*)d_in[7];
    P.Wq = (const float*)d_in[8];   P.bq = (const float*)d_in[9];
    P.Wk = (const float*)d_in[10];  P.bk = (const float*)d_in[11];
    P.Wv = (const float*)d_in[12];  P.bv = (const float*)d_in[13];
    P.Wo = (const float*)d_in[14];  P.bo = (const float*)d_in[15];
    P.W1 = (const float*)d_in[16];  P.b1 = (const float*)d_in[17];
    P.W2 = (const float*)d_in[18];  P.b2 = (const float*)d_in[19];
    P.ln1_g = (const float*)d_in[20]; P.ln1_b = (const float*)d_in[21];
    P.ln2_g = (const float*)d_in[22]; P.ln2_b = (const float*)d_in[23];
    P.lnf_g = (const float*)d_in[24]; P.lnf_b = (const float*)d_in[25];
    P.out = (float*)d_out;

    // ---- workspace layout (all 16B aligned) ----
    char* p = (char*)d_ws;
    P.bar = (int*)p; p += 4096;
    const size_t R = (size_t)NROWS * DMODEL;
    P.h    = (float*)p; p += R * 4;
    P.h1   = (float*)p; p += R * 4;
    P.tmp  = (float*)p; p += R * 4;
    P.qkvB  = (bf16*)p; p += (size_t)NROWS * NQKV * 2;
    P.hB    = (bf16*)p; p += R * 2;
    P.h1B   = (bf16*)p; p += R * 2;
    P.attB  = (bf16*)p; p += R * 2;
    P.ffn1B = (bf16*)p; p += (size_t)NROWS * FFD * 2;
    P.qkvT  = (bf16*)p; p += (size_t)4 * NQKV * DMODEL * 2;
    P.woT   = (bf16*)p; p += (size_t)4 * DMODEL * DMODEL * 2;
    P.w1T   = (bf16*)p; p += (size_t)4 * FFD * DMODEL * 2;
    P.w2T   = (bf16*)p; p += (size_t)4 * DMODEL * FFD * 2;

    hipMemsetAsync(P.bar, 0, 4096, stream);
    void* args[] = { (void*)&P };
    hipLaunchCooperativeKernel(reinterpret_cast<const void*>(mega_k),
                               dim3(NBLOCKS), dim3(NTHREADS), args, 0, stream);
}

// Round 8
// 441.162 us; speedup vs baseline: 2.2175x; 1.6381x over previous
//
#include <hip/hip_runtime.h>
#include <math.h>

// ---- problem constants ----
#define TT 80
#define BS 8
#define NA 6
#define DMODEL 768
#define DH 192
#define FFD 1024
#define NROWS 640
#define NQKV 2304

typedef __bf16 bf16;
typedef __bf16 bf16x8 __attribute__((ext_vector_type(8)));
typedef float  f32x4  __attribute__((ext_vector_type(4)));

// row stats (sum, sumsq) -> (mean, rstd) with LN eps
__device__ __forceinline__ void row_ms(const float* __restrict__ st, int row,
                                       float& m, float& rs) {
    float s1 = st[row * 2], s2 = st[row * 2 + 1];
    m = s1 * (1.0f / 768.0f);
    float var = s2 * (1.0f / 768.0f) - m * m;
    rs = rsqrtf(var + 1e-5f);
}

// ---------------- prep: weight transpose->bf16 + embedding + stats zero -----
// blocks 0..15359: one 32x32 transpose tile each (job decode verified R2/R3).
// blocks 15360..15999: embedding row r (t*8+b) + zero stats rows.
struct TJob { const float* src; bf16* dst; int ldsrc, Kd, n0, k0; };

__global__ __launch_bounds__(256) void prep_k(
        const float* __restrict__ x, const int* __restrict__ y,
        const int* __restrict__ ind_map,
        const float* __restrict__ skel_W, const float* __restrict__ skel_b,
        const float* __restrict__ muQ, const float* __restrict__ sigQ,
        const float* __restrict__ Wq, const float* __restrict__ Wk,
        const float* __restrict__ Wv, const float* __restrict__ Wo,
        const float* __restrict__ W1, const float* __restrict__ W2,
        bf16* __restrict__ qkvT, bf16* __restrict__ woT,
        bf16* __restrict__ w1T, bf16* __restrict__ w2T,
        float* __restrict__ h, bf16* __restrict__ h0B,
        float* __restrict__ stats) {
    __shared__ float tile[32][33];
    __shared__ float xrow[152];
    int bid = blockIdx.x, tid = threadIdx.x;
    if (bid < 15360) {
        TJob J;
        int l = bid / 3840, r = bid % 3840;
        if (r < 1728) {                             // QKV: K=768, N=2304
            int kt = r % 24, nt = r / 24;
            J.k0 = kt * 32; J.n0 = nt * 32; J.Kd = 768; J.ldsrc = 768;
            J.dst = qkvT + (size_t)l * NQKV * DMODEL;
            if (J.n0 < 768)       { J.src = Wq + (size_t)l * 589824 + J.n0; }
            else if (J.n0 < 1536) { J.src = Wk + (size_t)l * 589824 + (J.n0 - 768); }
            else                  { J.src = Wv + (size_t)l * 589824 + (J.n0 - 1536); }
        } else if (r < 2304) {                      // Wo: 768x768
            int r2 = r - 1728; int kt = r2 % 24, nt = r2 / 24;
            J.k0 = kt * 32; J.n0 = nt * 32; J.Kd = 768; J.ldsrc = 768;
            J.src = Wo + (size_t)l * 589824 + J.n0;
            J.dst = woT + (size_t)l * 589824;
        } else if (r < 3072) {                      // W1: K=768, N=1024
            int r2 = r - 2304; int kt = r2 % 24, nt = r2 / 24;
            J.k0 = kt * 32; J.n0 = nt * 32; J.Kd = 768; J.ldsrc = 1024;
            J.src = W1 + (size_t)l * 786432 + J.n0;
            J.dst = w1T + (size_t)l * 786432;
        } else {                                    // W2: K=1024, N=768
            int r2 = r - 3072; int kt = r2 % 32, nt = r2 / 32;
            J.k0 = kt * 32; J.n0 = nt * 32; J.Kd = 1024; J.ldsrc = 768;
            J.src = W2 + (size_t)l * 786432 + J.n0;
            J.dst = w2T + (size_t)l * 786432;
        }
        int tx = tid & 31, ty = tid >> 5;
#pragma unroll
        for (int i = 0; i < 4; i++) {
            int rr = ty + 8 * i;
            tile[rr][tx] = J.src[(size_t)(J.k0 + rr) * J.ldsrc + tx];
        }
        __syncthreads();
#pragma unroll
        for (int i = 0; i < 4; i++) {
            int rr = ty + 8 * i;
            J.dst[(size_t)(J.n0 + rr) * J.Kd + J.k0 + tx] = (bf16)tile[tx][rr];
        }
    } else {
        int r = bid - 15360;
        int t = r >> 3, b = r & 7;
        int c = tid;
        // zero stats rows for this row index (all 4 layers x {stats1,stats2})
        if (c < 16) {
            int arr = c >> 3, l = (c >> 1) & 3, j = c & 1;
            stats[arr * 5120 + l * 1280 + r * 2 + j] = 0.0f;
        }
        if (c < 150) xrow[c] = x[(b * 150 + c) * TT + t];
        __syncthreads();
        float acc = skel_b[c];
        for (int jf = 0; jf < 150; jf++) acc += xrow[jf] * skel_W[jf * 256 + c];
        int ind_t = ind_map[t * 8 + b];
        int yb = y[b * NA + ind_t];
        float cm = muQ[yb * 256 + c];
        float cs = sigQ[yb * 256 + c];
        int start = (t == 0) ? 0 : (t + 2);
        float div = expf((float)(c & ~1) * (-9.210340371976184f / 256.0f));
        float p0, p1, p2;
        if (c & 1) {
            p0 = cosf((float)start * div);
            p1 = cosf((float)(start + 1) * div);
            p2 = cosf((float)(start + 2) * div);
        } else {
            p0 = sinf((float)start * div);
            p1 = sinf((float)(start + 1) * div);
            p2 = sinf((float)(start + 2) * div);
        }
        float* hr = h + (size_t)r * DMODEL;
        float v0 = cm + p0, v1 = cs + p1, v2 = acc + p2;
        hr[c] = v0; hr[c + 256] = v1; hr[c + 512] = v2;
        bf16* hb = h0B + (size_t)r * DMODEL;
        hb[c] = (bf16)v0; hb[c + 256] = (bf16)v1; hb[c + 512] = (bf16)v2;
    }
}

// ---------------- bf16 MFMA GEMM: 64x64 tile, 256 threads, K-prefetch -------
// ANORM=0: A is bf16 [M,K].  ANORM=1: A is f32 + row stats + LN params,
// normalized inline during LDS staging (replaces a standalone LN dispatch).
// EPI 0: QKV epilogue (col-segmented bias, elu+1 on Q/K, bf16 out)
// EPI 1: bias + residual (RNORM: normalize resid inline) + f32 out
//        + per-row (sum,sumsq) atomics into stOut  (feeds the next LN)
// EPI 2: bias + relu, bf16 out
template <int EPI, int ANORM, int RNORM>
__global__ __launch_bounds__(256) void gemm_mfma(
        const bf16* __restrict__ Ab, const float* __restrict__ Af,
        const float* __restrict__ stA, const float* __restrict__ gA,
        const float* __restrict__ bA,
        const bf16* __restrict__ Bt,
        const float* __restrict__ bias_q, const float* __restrict__ bias_k,
        const float* __restrict__ bias_v,
        const float* __restrict__ residF, const float* __restrict__ stR,
        const float* __restrict__ gR, const float* __restrict__ bR,
        float* __restrict__ outF, bf16* __restrict__ outB,
        float* __restrict__ stOut, int N, int K) {
    __shared__ __attribute__((aligned(16))) bf16 As0[64][40];
    __shared__ __attribute__((aligned(16))) bf16 As1[64][40];
    __shared__ __attribute__((aligned(16))) bf16 Bs0[64][40];
    __shared__ __attribute__((aligned(16))) bf16 Bs1[64][40];
    int tid = threadIdx.x;
    int m0 = blockIdx.y * 64, n0 = blockIdx.x * 64;
    int w = tid >> 6, l = tid & 63;
    int lm = l & 15, lq = l >> 4;
    int sr = tid >> 2;
    int sk = (tid & 3) * 8;
    int arow = m0 + sr;
    const bf16* Brow = &Bt[(size_t)(n0 + sr) * K];
    f32x4 acc[4] = {};
    const bf16* Abrow = nullptr; const float* Afrow = nullptr;
    float mA = 0.f, rsA = 0.f;
    if (ANORM) {
        Afrow = &Af[(size_t)arow * K];
        row_ms(stA, arow, mA, rsA);
    } else {
        Abrow = &Ab[(size_t)arow * K];
    }
    // prefetch chunk 0
    uint4 a0, a1;
    f32x4 ax0a, ax0b, ax1a, ax1b;
    if (ANORM) {
        ax0a = *(const f32x4*)&Afrow[sk];      ax0b = *(const f32x4*)&Afrow[sk + 4];
        ax1a = *(const f32x4*)&Afrow[32 + sk]; ax1b = *(const f32x4*)&Afrow[36 + sk];
    } else {
        a0 = *(const uint4*)&Abrow[sk];
        a1 = *(const uint4*)&Abrow[32 + sk];
    }
    uint4 b0 = *(const uint4*)&Brow[sk];
    uint4 b1 = *(const uint4*)&Brow[32 + sk];
    for (int k0 = 0; k0 < K; k0 += 64) {
        __syncthreads();
        if (ANORM) {
            union { bf16 t[8]; uint4 u; } c0, c1;
            const float* gp = gA + k0 + sk;
            const float* bp = bA + k0 + sk;
#pragma unroll
            for (int j = 0; j < 4; j++) {
                c0.t[j]     = (bf16)((ax0a[j] - mA) * rsA * gp[j]      + bp[j]);
                c0.t[j + 4] = (bf16)((ax0b[j] - mA) * rsA * gp[j + 4]  + bp[j + 4]);
                c1.t[j]     = (bf16)((ax1a[j] - mA) * rsA * gp[32 + j] + bp[32 + j]);
                c1.t[j + 4] = (bf16)((ax1b[j] - mA) * rsA * gp[36 + j] + bp[36 + j]);
            }
            *(uint4*)&As0[sr][sk] = c0.u;
            *(uint4*)&As1[sr][sk] = c1.u;
        } else {
            *(uint4*)&As0[sr][sk] = a0;
            *(uint4*)&As1[sr][sk] = a1;
        }
        *(uint4*)&Bs0[sr][sk] = b0;
        *(uint4*)&Bs1[sr][sk] = b1;
        __syncthreads();
        int k2 = k0 + 64; if (k2 >= K) k2 = 0;   // tail: harmless re-read
        if (ANORM) {
            ax0a = *(const f32x4*)&Afrow[k2 + sk];      ax0b = *(const f32x4*)&Afrow[k2 + sk + 4];
            ax1a = *(const f32x4*)&Afrow[k2 + 32 + sk]; ax1b = *(const f32x4*)&Afrow[k2 + 36 + sk];
        } else {
            a0 = *(const uint4*)&Abrow[k2 + sk];
            a1 = *(const uint4*)&Abrow[k2 + 32 + sk];
        }
        b0 = *(const uint4*)&Brow[k2 + sk];
        b1 = *(const uint4*)&Brow[k2 + 32 + sk];
        bf16x8 af0 = *(bf16x8*)&As0[w * 16 + lm][lq * 8];
        bf16x8 af1 = *(bf16x8*)&As1[w * 16 + lm][lq * 8];
#pragma unroll
        for (int nb = 0; nb < 4; nb++) {
            bf16x8 bfr = *(bf16x8*)&Bs0[nb * 16 + lm][lq * 8];
            acc[nb] = __builtin_amdgcn_mfma_f32_16x16x32_bf16(af0, bfr, acc[nb], 0, 0, 0);
        }
#pragma unroll
        for (int nb = 0; nb < 4; nb++) {
            bf16x8 bfr = *(bf16x8*)&Bs1[nb * 16 + lm][lq * 8];
            acc[nb] = __builtin_amdgcn_mfma_f32_16x16x32_bf16(af1, bfr, acc[nb], 0, 0, 0);
        }
    }
    // ---- epilogue ----
    if (EPI == 1) {
        float mR4[4], rsR4[4];
        if (RNORM) {
#pragma unroll
            for (int r = 0; r < 4; r++)
                row_ms(stR, m0 + w * 16 + lq * 4 + r, mR4[r], rsR4[r]);
        }
        float s1[4] = {0.f, 0.f, 0.f, 0.f}, s2[4] = {0.f, 0.f, 0.f, 0.f};
#pragma unroll
        for (int nb = 0; nb < 4; nb++) {
            int col = n0 + nb * 16 + lm;
            float bia = bias_q[col];
            float gc = 0.f, bc = 0.f;
            if (RNORM) { gc = gR[col]; bc = bR[col]; }
#pragma unroll
            for (int r = 0; r < 4; r++) {
                int row = m0 + w * 16 + lq * 4 + r;
                float rv = residF[(size_t)row * N + col];
                if (RNORM) rv = (rv - mR4[r]) * rsR4[r] * gc + bc;
                float v = acc[nb][r] + bia + rv;
                outF[(size_t)row * N + col] = v;
                s1[r] += v; s2[r] += v * v;
            }
        }
        // reduce over lm (16 lanes hold this block's 64 cols of each row)
#pragma unroll
        for (int mk = 1; mk < 16; mk <<= 1) {
#pragma unroll
            for (int r = 0; r < 4; r++) {
                s1[r] += __shfl_xor(s1[r], mk, 64);
                s2[r] += __shfl_xor(s2[r], mk, 64);
            }
        }
        if (lm == 0) {
#pragma unroll
            for (int r = 0; r < 4; r++) {
                int row = m0 + w * 16 + lq * 4 + r;
                atomicAdd(&stOut[row * 2],     s1[r]);
                atomicAdd(&stOut[row * 2 + 1], s2[r]);
            }
        }
    } else {
#pragma unroll
        for (int nb = 0; nb < 4; nb++) {
            int col = n0 + nb * 16 + lm;
            float bia; bool do_elu = false;
            if (EPI == 0) {
                if (col < 768)       { bia = bias_q[col];        do_elu = true; }
                else if (col < 1536) { bia = bias_k[col - 768];  do_elu = true; }
                else                 { bia = bias_v[col - 1536]; }
            } else {
                bia = bias_q[col];
            }
#pragma unroll
            for (int r = 0; r < 4; r++) {
                int row = m0 + w * 16 + lq * 4 + r;
                float v = acc[nb][r] + bia;
                if (EPI == 0) {
                    if (do_elu) v = (v > 0.0f) ? (v + 1.0f) : expf(v);
                    outB[(size_t)row * N + col] = (bf16)v;
                } else {
                    outB[(size_t)row * N + col] = (bf16)fmaxf(v, 0.0f);
                }
            }
        }
    }
}

// ---------------- causal linear attention: 96 blocks (x3 PV split) ----------
// Verified numerically in the R3 run (flat megakernel variant, plain loads).
__global__ __launch_bounds__(320) void attn_k(
        const bf16* __restrict__ qkvB, bf16* __restrict__ att) {
    __shared__ __attribute__((aligned(16))) char smem[64000];
    bf16* Qs = (bf16*)smem;            // [80][200]
    bf16* Ks = (bf16*)(smem + 32000);  // [80][200]
    bf16* Aij = (bf16*)smem;           // [80][104]  (overlays Qs after phase 1)
    bf16* VT = (bf16*)(smem + 16640);  // [192][104] (overlays Ks)
    int bh = blockIdx.x / 3, part = blockIdx.x % 3;
    int bb = bh >> 2, hd = bh & 3;
    int tid = threadIdx.x;
    int w = tid >> 6, l = tid & 63;
    int lm = l & 15, lq = l >> 4;

    uint4 vreg[6];
#pragma unroll
    for (int u = 0; u < 6; u++) {
        int c = tid + 320 * u;
        int t = c / 24, cc = c % 24;
        int d0 = cc * 8;
        size_t g = (size_t)(t * 8 + bb) * NQKV + hd * DH + d0;
        uint4 qv = *(const uint4*)&qkvB[g];
        uint4 kv = *(const uint4*)&qkvB[g + 768];
        vreg[u]  = *(const uint4*)&qkvB[g + 1536];
        *(uint4*)&Qs[t * 200 + d0] = qv;
        *(uint4*)&Ks[t * 200 + d0] = kv;
    }
    __syncthreads();

    f32x4 acc[5] = {};
#pragma unroll
    for (int k0 = 0; k0 < 192; k0 += 32) {
        bf16x8 af = *(bf16x8*)&Qs[(w * 16 + lm) * 200 + lq * 8 + k0];
#pragma unroll
        for (int nb = 0; nb < 5; nb++) {
            bf16x8 bfr = *(bf16x8*)&Ks[(nb * 16 + lm) * 200 + lq * 8 + k0];
            acc[nb] = __builtin_amdgcn_mfma_f32_16x16x32_bf16(af, bfr, acc[nb], 0, 0, 0);
        }
    }
    float mval[5][4];
    float rs[4] = {0.f, 0.f, 0.f, 0.f};
#pragma unroll
    for (int nb = 0; nb < 5; nb++)
#pragma unroll
        for (int r = 0; r < 4; r++) {
            int t = w * 16 + lq * 4 + r, tau = nb * 16 + lm;
            float v = (tau <= t) ? acc[nb][r] : 0.0f;
            mval[nb][r] = v;
            rs[r] += v;
        }
#pragma unroll
    for (int mk = 1; mk < 16; mk <<= 1)
#pragma unroll
        for (int r = 0; r < 4; r++) rs[r] += __shfl_xor(rs[r], mk, 64);
    float inv[4];
#pragma unroll
    for (int r = 0; r < 4; r++) inv[r] = 1.0f / (rs[r] + 1e-6f);

    __syncthreads();

#pragma unroll
    for (int nb = 0; nb < 5; nb++)
#pragma unroll
        for (int r = 0; r < 4; r++)
            Aij[(w * 16 + lq * 4 + r) * 104 + nb * 16 + lm] = (bf16)mval[nb][r];
    *(uint2*)&Aij[(tid >> 2) * 104 + 80 + (tid & 3) * 4] = make_uint2(0u, 0u);
#pragma unroll
    for (int u = 0; u < 6; u++) {
        int c = tid + 320 * u;
        int t = c / 24, cc = c % 24;
        int d0 = cc * 8;
        bf16 tmp8[8];
        *(uint4*)tmp8 = vreg[u];
#pragma unroll
        for (int j = 0; j < 8; j++) VT[(d0 + j) * 104 + t] = tmp8[j];
    }
    if (tid < 192) {
        *(uint4*)&VT[tid * 104 + 80] = make_uint4(0u, 0u, 0u, 0u);
        *(uint4*)&VT[tid * 104 + 88] = make_uint4(0u, 0u, 0u, 0u);
    }
    __syncthreads();

#pragma unroll 1
    for (int nc = part * 4; nc < part * 4 + 4; nc++) {
        f32x4 a2 = {};
#pragma unroll
        for (int k0 = 0; k0 < 96; k0 += 32) {
            bf16x8 af = *(bf16x8*)&Aij[(w * 16 + lm) * 104 + lq * 8 + k0];
            bf16x8 bfr = *(bf16x8*)&VT[(nc * 16 + lm) * 104 + lq * 8 + k0];
            a2 = __builtin_amdgcn_mfma_f32_16x16x32_bf16(af, bfr, a2, 0, 0, 0);
        }
#pragma unroll
        for (int r = 0; r < 4; r++) {
            int t = w * 16 + lq * 4 + r;
            att[(size_t)(t * 8 + bb) * DMODEL + hd * DH + nc * 16 + lm] =
                (bf16)(a2[r] * inv[r]);
        }
    }
}

// ---------------- final: inline ln2(tmp2) then lnf, gather outputs ----------
__device__ __forceinline__ float block_reduce_sum256(float v, float* sm4) {
#pragma unroll
    for (int off = 32; off > 0; off >>= 1) v += __shfl_down(v, off, 64);
    int lane = threadIdx.x & 63, wid = threadIdx.x >> 6;
    if (lane == 0) sm4[wid] = v;
    __syncthreads();
    float r = sm4[0] + sm4[1] + sm4[2] + sm4[3];
    __syncthreads();
    return r;
}

__global__ __launch_bounds__(256) void final_k(
        const float* __restrict__ tmp2, const float* __restrict__ st2,
        const float* __restrict__ g2, const float* __restrict__ b2,
        const int* __restrict__ act_ts,
        const float* __restrict__ gf, const float* __restrict__ bf_,
        float* __restrict__ out) {
    __shared__ float sm4[4];
    int ba = blockIdx.x;
    int b = ba / NA;
    int ts = act_ts[ba];
    int t = ts - 1; if (t < 0) t = 0;
    int row = t * 8 + b;
    const float* xr = tmp2 + (size_t)row * DMODEL;
    int c = threadIdx.x;
    float m2, rs2;
    row_ms(st2, row, m2, rs2);
    float x0 = (xr[c]       - m2) * rs2 * g2[c]       + b2[c];
    float x1 = (xr[c + 256] - m2) * rs2 * g2[c + 256] + b2[c + 256];
    float x2 = (xr[c + 512] - m2) * rs2 * g2[c + 512] + b2[c + 512];
    float m = block_reduce_sum256(x0 + x1 + x2, sm4) * (1.0f / 768.0f);
    float d0 = x0 - m, d1 = x1 - m, d2 = x2 - m;
    float v = block_reduce_sum256(d0 * d0 + d1 * d1 + d2 * d2, sm4) * (1.0f / 768.0f);
    float r = rsqrtf(v + 1e-5f);
    out[ba * 256 + c]            = d0 * r * gf[c] + bf_[c];                 // mu
    out[48 * 256 + ba * 256 + c] = d1 * r * gf[c + 256] + bf_[c + 256];     // logvar
}

extern "C" void kernel_launch(void* const* d_in, const int* in_sizes, int n_in,
                              void* d_out, int out_size, void* d_ws, size_t ws_size,
                              hipStream_t stream) {
    const float* x       = (const float*)d_in[0];
    const int*   y       = (const int*)d_in[1];
    const int*   ind_map = (const int*)d_in[2];
    const int*   act_ts  = (const int*)d_in[3];
    const float* skel_W  = (const float*)d_in[4];
    const float* skel_b  = (const float*)d_in[5];
    const float* muQ     = (const float*)d_in[6];
    const float* sigQ    = (const float*)d_in[7];
    const float* Wq = (const float*)d_in[8];   const float* bq = (const float*)d_in[9];
    const float* Wk = (const float*)d_in[10];  const float* bk = (const float*)d_in[11];
    const float* Wv = (const float*)d_in[12];  const float* bv = (const float*)d_in[13];
    const float* Wo = (const float*)d_in[14];  const float* bo = (const float*)d_in[15];
    const float* W1 = (const float*)d_in[16];  const float* b1 = (const float*)d_in[17];
    const float* W2 = (const float*)d_in[18];  const float* b2 = (const float*)d_in[19];
    const float* ln1_g = (const float*)d_in[20]; const float* ln1_b = (const float*)d_in[21];
    const float* ln2_g = (const float*)d_in[22]; const float* ln2_b = (const float*)d_in[23];
    const float* lnf_g = (const float*)d_in[24]; const float* lnf_b = (const float*)d_in[25];
    float* out = (float*)d_out;

    // ---- workspace layout (all 16B aligned) ----
    char* p = (char*)d_ws;
    const size_t R = (size_t)NROWS * DMODEL;
    float* h     = (float*)p; p += R * 4;                       // embed out (f32)
    float* tmp1  = (float*)p; p += R * 4;                       // pre-LN1
    float* tmp2  = (float*)p; p += R * 4;                       // pre-LN2
    float* stats = (float*)p; p += 10240 * 4;                   // [2][4][640][2]
    bf16* h0B    = (bf16*)p;  p += R * 2;
    bf16* qkvB   = (bf16*)p;  p += (size_t)NROWS * NQKV * 2;
    bf16* attB   = (bf16*)p;  p += R * 2;
    bf16* ffn1B  = (bf16*)p;  p += (size_t)NROWS * FFD * 2;
    bf16* qkvT   = (bf16*)p;  p += (size_t)4 * NQKV * DMODEL * 2;
    bf16* woT    = (bf16*)p;  p += (size_t)4 * DMODEL * DMODEL * 2;
    bf16* w1T    = (bf16*)p;  p += (size_t)4 * FFD * DMODEL * 2;
    bf16* w2T    = (bf16*)p;  p += (size_t)4 * DMODEL * FFD * 2;

    // 1. transpose + embed + stats zero (self-reinitializing each replay)
    prep_k<<<16000, 256, 0, stream>>>(x, y, ind_map, skel_W, skel_b, muQ, sigQ,
                                      Wq, Wk, Wv, Wo, W1, W2,
                                      qkvT, woT, w1T, w2T, h, h0B, stats);

    dim3 gQKV(NQKV / 64, 10);
    dim3 g768(12, 10);
    dim3 g1024(16, 10);
    for (int l = 0; l < 4; l++) {
        const bf16* qkvTl = qkvT + (size_t)l * NQKV * DMODEL;
        const bf16* woTl  = woT  + (size_t)l * DMODEL * DMODEL;
        const bf16* w1Tl  = w1T  + (size_t)l * FFD * DMODEL;
        const bf16* w2Tl  = w2T  + (size_t)l * DMODEL * FFD;
        float* st1 = stats + l * 1280;
        float* st2 = stats + 5120 + l * 1280;
        const float* st2p = stats + 5120 + (l - 1) * 1280;       // prev layer
        const float* g2p = ln2_g + (l - 1) * DMODEL;
        const float* b2p = ln2_b + (l - 1) * DMODEL;

        // QKV: A = h0 (l=0) or norm2(tmp2_prev) inline
        if (l == 0)
            gemm_mfma<0, 0, 0><<<gQKV, 256, 0, stream>>>(
                h0B, nullptr, nullptr, nullptr, nullptr, qkvTl,
                bq, bk, bv,
                nullptr, nullptr, nullptr, nullptr,
                nullptr, qkvB, nullptr, NQKV, DMODEL);
        else
            gemm_mfma<0, 1, 0><<<gQKV, 256, 0, stream>>>(
                nullptr, tmp2, st2p, g2p, b2p, qkvTl,
                bq + l * DMODEL, bk + l * DMODEL, bv + l * DMODEL,
                nullptr, nullptr, nullptr, nullptr,
                nullptr, qkvB, nullptr, NQKV, DMODEL);

        attn_k<<<96, 320, 0, stream>>>(qkvB, attB);

        // Wo: tmp1 = att@Wo + bo + h_in, + stats1 atomics
        if (l == 0)
            gemm_mfma<1, 0, 0><<<g768, 256, 0, stream>>>(
                attB, nullptr, nullptr, nullptr, nullptr, woTl,
                bo, nullptr, nullptr,
                h, nullptr, nullptr, nullptr,
                tmp1, nullptr, st1, DMODEL, DMODEL);
        else
            gemm_mfma<1, 0, 1><<<g768, 256, 0, stream>>>(
                attB, nullptr, nullptr, nullptr, nullptr, woTl,
                bo + l * DMODEL, nullptr, nullptr,
                tmp2, st2p, g2p, b2p,
                tmp1, nullptr, st1, DMODEL, DMODEL);

        // FFN1: A = norm1(tmp1) inline; relu -> ffn1B
        gemm_mfma<2, 1, 0><<<g1024, 256, 0, stream>>>(
            nullptr, tmp1, st1, ln1_g + l * DMODEL, ln1_b + l * DMODEL, w1Tl,
            b1 + l * FFD, nullptr, nullptr,
            nullptr, nullptr, nullptr, nullptr,
            nullptr, ffn1B, nullptr, FFD, DMODEL);

        // FFN2: tmp2 = ffn1@W2 + b2 + norm1(tmp1), + stats2 atomics
        gemm_mfma<1, 0, 1><<<g768, 256, 0, stream>>>(
            ffn1B, nullptr, nullptr, nullptr, nullptr, w2Tl,
            b2 + l * DMODEL, nullptr, nullptr,
            tmp1, st1, ln1_g + l * DMODEL, ln1_b + l * DMODEL,
            tmp2, nullptr, st2, DMODEL, FFD);
    }

    final_k<<<48, 256, 0, stream>>>(tmp2, stats + 5120 + 3 * 1280,
                                    ln2_g + 3 * DMODEL, ln2_b + 3 * DMODEL,
                                    act_ts, lnf_g, lnf_b, out);
}